// Round 8
// baseline (246.363 us; speedup 1.0000x reference)
//
#include <hip/hip_runtime.h>

// NMS3D: x (4,2,64,256,256) f32, 3x3x3 neighborhood-max excluding center,
// edge padding == index clamping (exact match, incl. zeroed boundary shell).
//
// R8: barrier-free DMA ring (R7) + block... no: WAVE-private 6-row slab
// reuse (R5's traffic cut without its barriers). Evidence: duration is
// invariant (~80us) across occupancy 34-75% and prefetch depth -> not
// latency; invariant L1<->L2 port traffic ~12.5-13 B/cyc/CU across
// R1/R2/R7 and the harness fill (10.9) -> per-CU vmem-port byte ceiling.
// Cut port bytes: each wave DMAs 6 rows/slice, emits 4 rows; DC=16 halves
// z-halo. 2.69 KB port traffic per 1 KB output (was 4.75).
// Wave-private 3-slot LDS ring, NO __syncthreads -> no vmcnt(0) drains;
// 2 slices in flight; hand-placed partial s_waitcnt vmcnt(N).

constexpr int D_    = 64;
constexpr int H_    = 256;
constexpr int W_    = 256;
constexpr int HW_   = H_ * W_;
constexpr int NVOL  = 8;    // B * CH
constexpr int DC    = 16;   // depth slices emitted per block
constexpr int R_    = 4;    // output rows per wave
constexpr int SLAB  = R_ + 2;
constexpr int WAVES = 2;

__device__ __forceinline__ float f3(float a, float b, float c) {
    return fmaxf(fmaxf(a, b), c);
}

// one row (1 KB) global->LDS DMA: lane i moves 16 B; lds base wave-uniform
__device__ __forceinline__ void dma_row(const float* g, float* l) {
    __builtin_amdgcn_global_load_lds(
        (const __attribute__((address_space(1))) void*)g,
        (__attribute__((address_space(3))) void*)l,
        16, 0, 0);
}

__global__ __launch_bounds__(128, 2)
void nms3d(const float* __restrict__ x, float* __restrict__ out)
{
    __shared__ float buf[WAVES][3][SLAB][W_];   // 36 KB

    const int tx = threadIdx.x;                       // 0..63, W via float4
    const int ty = threadIdx.y;                       // wave id 0..1
    const int h0 = (blockIdx.y * WAVES + ty) * R_;    // first output row
    const int n  = blockIdx.z;
    const int z0 = blockIdx.x * DC;
    const int c  = tx << 2;

    const float* __restrict__ base = x   + (size_t)n * D_ * HW_;
    float* __restrict__       ob   = out + (size_t)n * D_ * HW_;

    int gj[SLAB];                                     // staged global rows
#pragma unroll
    for (int j = 0; j < SLAB; ++j) gj[j] = min(max(h0 - 1 + j, 0), H_ - 1);

    // stage slice s (z = z0-1+s clamped) into ring slot `slot`: 6 DMAs
    auto stage = [&](int s, int slot) {
        const int zc = min(max(z0 - 1 + s, 0), D_ - 1);
        const float* sp = base + (size_t)zc * HW_;
        float* sl = &buf[ty][slot][0][0];
#pragma unroll
        for (int j = 0; j < SLAB; ++j)
            dma_row(sp + gj[j] * W_ + c, sl + j * W_);
    };

    // rolling depth state per output row
    float4 vpp[R_], vp[R_], c8p[R_], vb[R_];
#pragma unroll
    for (int i = 0; i < R_; ++i) {
        vpp[i] = {0,0,0,0}; vp[i] = {0,0,0,0};
        c8p[i] = {0,0,0,0}; vb[i] = {0,0,0,0};
    }

    // compute slice in ring slot `sl` (depth zi); store planes when st
    auto body = [&](int sl, int zi, bool st) {
        const float* lp = &buf[ty][sl][0][0];
        float4 s[SLAB];
#pragma unroll
        for (int j = 0; j < SLAB; ++j)
            s[j] = *(const float4*)(lp + j * W_ + c);
#pragma unroll
        for (int i = 0; i < R_; ++i) {
            const float4 b = s[i + 1];
            float4 va;
            va.x = fmaxf(s[i].x, s[i+2].x); va.y = fmaxf(s[i].y, s[i+2].y);
            va.z = fmaxf(s[i].z, s[i+2].z); va.w = fmaxf(s[i].w, s[i+2].w);

            float vaL = __shfl_up(va.w, 1);   if (tx == 0)  vaL = va.x;
            float vaR = __shfl_down(va.x, 1); if (tx == 63) vaR = va.w;
            float bL  = __shfl_up(b.w, 1);    if (tx == 0)  bL  = b.x;
            float bR  = __shfl_down(b.x, 1);  if (tx == 63) bR  = b.w;

            float4 hv, nb, c8, cu;
            hv.x = f3(vaL, va.x, va.y);  hv.y = f3(va.x, va.y, va.z);
            hv.z = f3(va.y, va.z, va.w); hv.w = f3(va.z, va.w, vaR);
            nb.x = fmaxf(bL, b.y);   nb.y = fmaxf(b.x, b.z);
            nb.z = fmaxf(b.y, b.w);  nb.w = fmaxf(b.z, bR);
            c8.x = fmaxf(hv.x, nb.x); c8.y = fmaxf(hv.y, nb.y);
            c8.z = fmaxf(hv.z, nb.z); c8.w = fmaxf(hv.w, nb.w);
            cu.x = fmaxf(c8.x, b.x);  cu.y = fmaxf(c8.y, b.y);
            cu.z = fmaxf(c8.z, b.z);  cu.w = fmaxf(c8.w, b.w);

            if (st) {
                // out[zi-1]: max_nc = max(vmax9[zi-2], cross8[zi-1], vmax9[zi])
                float4 mx, o;
                mx.x = f3(vpp[i].x, c8p[i].x, cu.x);
                mx.y = f3(vpp[i].y, c8p[i].y, cu.y);
                mx.z = f3(vpp[i].z, c8p[i].z, cu.z);
                mx.w = f3(vpp[i].w, c8p[i].w, cu.w);
                o.x = vb[i].x > mx.x ? vb[i].x : 0.0f;
                o.y = vb[i].y > mx.y ? vb[i].y : 0.0f;
                o.z = vb[i].z > mx.z ? vb[i].z : 0.0f;
                o.w = vb[i].w > mx.w ? vb[i].w : 0.0f;
                *(float4*)(ob + (size_t)(zi - 1) * HW_ + (size_t)(h0 + i) * W_ + c) = o;
            }
            vpp[i] = vp[i]; vp[i] = cu; c8p[i] = c8; vb[i] = b;
        }
    };

    // ---- pipeline ----
    // vm-op issue order: S0 S1 | B0: S2 w | B1: S3 w | B2: S4 w st |
    // B3..B(DC-1): S(t+2) w st | B(DC): w st | B(DC+1): w st
    // (each S = 6 DMAs, each st = 4 stores; vmcnt counts both, in order)
    stage(0, 0);
    stage(1, 1);

    stage(2, 2);                                     // t=0: need S0 -> 12 younger
    asm volatile("s_waitcnt vmcnt(12)" ::: "memory");
    body(0, z0 - 1, false);

    stage(3, 0);                                     // t=1: need S1 -> 12
    asm volatile("s_waitcnt vmcnt(12)" ::: "memory");
    body(1, z0, false);

    stage(4, 1);                                     // t=2: need S2 -> 12
    asm volatile("s_waitcnt vmcnt(12)" ::: "memory");
    body(2, z0 + 1, true);

    int sl = 0;                                      // slot of body t=3
#pragma unroll 1
    for (int t = 3; t < DC; ++t) {
        const int slot_stage = (sl + 2) >= 3 ? (sl - 1) : (sl + 2);
        stage(t + 2, slot_stage);
        // need S(t): t==3 -> 16 younger; t>=4 -> 20 (16 over-waits st(t-2), free)
        asm volatile("s_waitcnt vmcnt(16)" ::: "memory");
        body(sl, z0 - 1 + t, true);
        sl = (sl == 2) ? 0 : sl + 1;
    }

    // t=DC: need S(DC) -> 14 younger
    asm volatile("s_waitcnt vmcnt(14)" ::: "memory");
    body(sl, z0 - 1 + DC, true);
    sl = (sl == 2) ? 0 : sl + 1;

    // t=DC+1: need S(DC+1) -> 8 younger
    asm volatile("s_waitcnt vmcnt(8)" ::: "memory");
    body(sl, z0 + DC, true);
}

extern "C" void kernel_launch(void* const* d_in, const int* in_sizes, int n_in,
                              void* d_out, int out_size, void* d_ws, size_t ws_size,
                              hipStream_t stream)
{
    const float* x = (const float*)d_in[0];
    float* out = (float*)d_out;
    dim3 block(64, WAVES, 1);                         // 128 threads = 2 waves
    dim3 grid(D_ / DC, H_ / (WAVES * R_), NVOL);      // 4 x 32 x 8 = 1024
    nms3d<<<grid, block, 0, stream>>>(x, out);
}